// Round 1
// baseline (727.370 us; speedup 1.0000x reference)
//
#include <hip/hip_runtime.h>

#define N_NODES 100000
#define N_EDGES 1200000
#define IN_F 128
#define HID 64
#define BN_EPS 1e-5f
#define SCAN_NBLK 98   // 98 * 1024 >= 100000

// ---------------- CSR / degree kernels ----------------

__global__ void k_hist(const int* __restrict__ dst, int* __restrict__ cnt) {
    int e = blockIdx.x * 256 + threadIdx.x;
    if (e < N_EDGES) atomicAdd(&cnt[dst[e]], 1);
}

__global__ void k_dinv(const int* __restrict__ cnt, float* __restrict__ dinv) {
    int i = blockIdx.x * 256 + threadIdx.x;
    if (i < N_NODES) dinv[i] = rsqrtf((float)(cnt[i] + 1));  // +1 self loop
}

// block-local exclusive scan: 256 threads x 4 elems = 1024 per block
__global__ void k_scan_block(const int* __restrict__ cnt, int* __restrict__ outv,
                             int* __restrict__ bsum) {
    __shared__ int lds[256];
    int t = threadIdx.x;
    int base = blockIdx.x * 1024 + t * 4;
    int v[4];
#pragma unroll
    for (int q = 0; q < 4; q++) {
        int idx = base + q;
        v[q] = (idx < N_NODES) ? cnt[idx] : 0;
    }
    int tot = v[0] + v[1] + v[2] + v[3];
    lds[t] = tot;
    __syncthreads();
    int x = tot;
    for (int off = 1; off < 256; off <<= 1) {
        int y = (t >= off) ? lds[t - off] : 0;
        __syncthreads();
        x += y;
        lds[t] = x;
        __syncthreads();
    }
    int run = x - tot;  // exclusive prefix of this thread
    if (t == 255) bsum[blockIdx.x] = x;
#pragma unroll
    for (int q = 0; q < 4; q++) {
        int idx = base + q;
        if (idx < N_NODES) outv[idx] = run;
        run += v[q];
    }
}

__global__ void k_scan_bsum(int* bsum, int nb) {
    if (threadIdx.x == 0 && blockIdx.x == 0) {
        int run = 0;
        for (int b = 0; b < nb; b++) { int t = bsum[b]; bsum[b] = run; run += t; }
    }
}

__global__ void k_scan_add(int* __restrict__ row_ptr, const int* __restrict__ bsum,
                           int* __restrict__ cursor) {
    int i = blockIdx.x * 256 + threadIdx.x;
    if (i < N_NODES) {
        int v = row_ptr[i] + bsum[i >> 10];
        row_ptr[i] = v;
        cursor[i] = v;
    }
    if (i == 0) row_ptr[N_NODES] = N_EDGES;
}

__global__ void k_fill(const int* __restrict__ src, const int* __restrict__ dstv,
                       const float* __restrict__ dinv, int* __restrict__ cursor,
                       int* __restrict__ col, float* __restrict__ val) {
    int e = blockIdx.x * 256 + threadIdx.x;
    if (e < N_EDGES) {
        int s = src[e], d = dstv[e];
        int pos = atomicAdd(&cursor[d], 1);
        col[pos] = s;
        val[pos] = dinv[s] * dinv[d];
    }
}

// ---------------- BatchNorm stats ----------------
// column sums + sumsq over the node dim; optional relu on read.
template <int C, bool RELU>
__global__ void k_stats(const float* __restrict__ h, float* __restrict__ sums) {
    __shared__ float l1[256], l2[256];
    int t = threadIdx.x;
    int c = t & (C - 1);
    const int rpb = 256 / C;
    float s1 = 0.f, s2 = 0.f;
    for (int r = blockIdx.x * rpb + t / C; r < N_NODES; r += gridDim.x * rpb) {
        float v = h[r * C + c];
        if (RELU) v = fmaxf(v, 0.f);
        s1 += v;
        s2 += v * v;
    }
    l1[t] = s1;
    l2[t] = s2;
    __syncthreads();
    if (t < C) {
        for (int r = 1; r < rpb; r++) { s1 += l1[r * C + t]; s2 += l2[r * C + t]; }
        atomicAdd(&sums[t], s1);
        atomicAdd(&sums[C + t], s2);
    }
}

// scale/shift from stats; also shiftW[j] = sum_k shift[k]*W[k][j]
template <int C>
__global__ void k_finalize(const float* __restrict__ sums, const float* __restrict__ gamma,
                           const float* __restrict__ beta, const float* __restrict__ W,
                           float* __restrict__ scaleshift, float* __restrict__ shiftW) {
    __shared__ float sh[C];
    int t = threadIdx.x;  // blockDim = 128
    if (t < C) {
        float m = sums[t] * (1.0f / N_NODES);
        float var = sums[C + t] * (1.0f / N_NODES) - m * m;
        float sc = gamma[t] * rsqrtf(var + BN_EPS);
        float s = beta[t] - m * sc;
        scaleshift[t] = sc;
        scaleshift[C + t] = s;
        sh[t] = s;
    }
    __syncthreads();
    if (t < HID) {
        float acc = 0.f;
#pragma unroll 4
        for (int k = 0; k < C; k++) acc += sh[k] * W[k * HID + t];
        shiftW[t] = acc;
    }
}

// ---------------- fused BN-apply + GEMM ----------------
// out[i][j] = sum_k g(h[i][k]) * (scale[k]*W[k][j]) + shiftW[j]  (+bias, relu)
// g = relu or identity. 256 thr = 32 rows x 8 colgroups; 8 outputs/thread.
template <int K, bool RELU_IN, bool OUT_BIAS_RELU>
__global__ __launch_bounds__(256) void k_gemm(const float* __restrict__ h,
                                              const float* __restrict__ W,
                                              const float* __restrict__ scaleshift,
                                              const float* __restrict__ shiftW,
                                              const float* __restrict__ bias,
                                              float* __restrict__ out) {
    __shared__ float Wl[K][HID];
    for (int idx = threadIdx.x; idx < K * HID; idx += 256) {
        int k = idx / HID;
        Wl[k][idx % HID] = W[idx] * scaleshift[k];  // fold BN scale into W
    }
    __syncthreads();
    int t = threadIdx.x;
    int row = blockIdx.x * 32 + (t >> 3);  // N_NODES % 32 == 0
    int j0 = (t & 7) * 8;
    const float* hr = h + row * K;
    float acc[8];
#pragma unroll
    for (int jj = 0; jj < 8; jj++) acc[jj] = shiftW[j0 + jj];
    for (int k = 0; k < K; k += 4) {
        float4 a4 = *reinterpret_cast<const float4*>(hr + k);
        float av[4] = {a4.x, a4.y, a4.z, a4.w};
#pragma unroll
        for (int kk = 0; kk < 4; kk++) {
            float v = av[kk];
            if (RELU_IN) v = fmaxf(v, 0.f);
#pragma unroll
            for (int jj = 0; jj < 8; jj++) acc[jj] += v * Wl[k + kk][j0 + jj];
        }
    }
    float* o = out + row * HID + j0;
    float4 o0, o1;
    float vv[8];
#pragma unroll
    for (int jj = 0; jj < 8; jj++) {
        float v = acc[jj];
        if (OUT_BIAS_RELU) v = fmaxf(v + bias[j0 + jj], 0.f);
        vv[jj] = v;
    }
    o0.x = vv[0]; o0.y = vv[1]; o0.z = vv[2]; o0.w = vv[3];
    o1.x = vv[4]; o1.y = vv[5]; o1.z = vv[6]; o1.w = vv[7];
    *reinterpret_cast<float4*>(o) = o0;
    *reinterpret_cast<float4*>(o + 4) = o1;
}

// ---------------- per-node gather aggregation ----------------
// out[i][j] = bias[j] + t[i][j]*dinv[i]^2 + sum_{e in CSR(i)} t[col[e]][j]*val[e]
template <bool RELU_OUT>
__global__ void k_agg(const float* __restrict__ t_mat, const int* __restrict__ row_ptr,
                      const int* __restrict__ col, const float* __restrict__ val,
                      const float* __restrict__ dinv, const float* __restrict__ bias,
                      float* __restrict__ out) {
    int wid = (blockIdx.x * 256 + threadIdx.x) >> 6;  // one wave per node
    int lane = threadIdx.x & 63;
    if (wid >= N_NODES) return;
    float di = dinv[wid];
    float acc = bias[lane] + t_mat[wid * HID + lane] * di * di;
    int e0 = row_ptr[wid], e1 = row_ptr[wid + 1];
    for (int e = e0; e < e1; e++) {
        int s = col[e];        // wave-uniform -> scalar load
        float w = val[e];
        acc += t_mat[s * HID + lane] * w;
    }
    out[wid * HID + lane] = RELU_OUT ? fmaxf(acc, 0.f) : acc;
}

// ---------------- launch ----------------

extern "C" void kernel_launch(void* const* d_in, const int* in_sizes, int n_in,
                              void* d_out, int out_size, void* d_ws, size_t ws_size,
                              hipStream_t stream) {
    const float* x = (const float*)d_in[0];
    const int* ei = (const int*)d_in[1];
    const int* src = ei;
    const int* dst = ei + N_EDGES;
    const float* bn0_g = (const float*)d_in[2];
    const float* bn0_b = (const float*)d_in[3];
    const float* W0 = (const float*)d_in[4];
    const float* b0 = (const float*)d_in[5];
    const float* bns_g = (const float*)d_in[6];
    const float* bns_b = (const float*)d_in[7];
    const float* Ws = (const float*)d_in[8];
    const float* bs = (const float*)d_in[9];
    float* out = (float*)d_out;
    char* ws = (char*)d_ws;

    // workspace layout (bytes, 256-aligned)
    float* dinv    = (float*)(ws + 0);          //  400,128
    int*   cnt     = (int*)(ws + 400128);       //  400,128
    int*   row_ptr = (int*)(ws + 800256);       //  400,128 (N+1 ints)
    int*   cursor  = (int*)(ws + 1200384);      //  400,128
    int*   col     = (int*)(ws + 1600512);      // 4,800,000
    float* val     = (float*)(ws + 6400512);    // 4,800,000
    int*   bsum    = (int*)(ws + 11200512);     //      512
    float* sums    = (float*)(ws + 11201024);   //    1,024
    float* scsh    = (float*)(ws + 11202048);   //    1,024
    float* shiftW  = (float*)(ws + 11203072);   //      256
    float* bufA    = (float*)(ws + 11203328);   // 25,600,000
    float* bufB    = (float*)(ws + 36803328);   // 25,600,000  -> total 62,403,328 B

    const int EB = (N_EDGES + 255) / 256;
    const int NB = (N_NODES + 255) / 256;
    const int GEMM_B = N_NODES / 32;        // 3125
    const int AGG_B = (N_NODES + 3) / 4;    // 25000 (4 waves/block)

    // ---- CSR build (layer-invariant) ----
    hipMemsetAsync(cnt, 0, N_NODES * sizeof(int), stream);
    k_hist<<<EB, 256, 0, stream>>>(dst, cnt);
    k_dinv<<<NB, 256, 0, stream>>>(cnt, dinv);
    k_scan_block<<<SCAN_NBLK, 256, 0, stream>>>(cnt, row_ptr, bsum);
    k_scan_bsum<<<1, 64, 0, stream>>>(bsum, SCAN_NBLK);
    k_scan_add<<<NB, 256, 0, stream>>>(row_ptr, bsum, cursor);
    k_fill<<<EB, 256, 0, stream>>>(src, dst, dinv, cursor, col, val);

    // ---- layer 0: BN(x) -> Linear -> ReLU -> bufA ----
    hipMemsetAsync(sums, 0, 2 * IN_F * sizeof(float), stream);
    k_stats<IN_F, false><<<400, 256, 0, stream>>>(x, sums);
    k_finalize<IN_F><<<1, 128, 0, stream>>>(sums, bn0_g, bn0_b, W0, scsh, shiftW);
    k_gemm<IN_F, false, true><<<GEMM_B, 256, 0, stream>>>(x, W0, scsh, shiftW, b0, bufA);

    // ---- layer 1: BN(bufA) -> W1 -> aggregate -> d_out (pre-relu) ----
    hipMemsetAsync(sums, 0, 2 * HID * sizeof(float), stream);
    k_stats<HID, false><<<400, 256, 0, stream>>>(bufA, sums);
    k_finalize<HID><<<1, 128, 0, stream>>>(sums, bns_g, bns_b, Ws, scsh, shiftW);
    k_gemm<HID, false, false><<<GEMM_B, 256, 0, stream>>>(bufA, Ws, scsh, shiftW, nullptr, bufB);
    k_agg<false><<<AGG_B, 256, 0, stream>>>(bufB, row_ptr, col, val, dinv, bs, out);

    // ---- layer 2: BN(relu(d_out)) -> W2 -> aggregate -> bufB (pre-relu) ----
    hipMemsetAsync(sums, 0, 2 * HID * sizeof(float), stream);
    k_stats<HID, true><<<400, 256, 0, stream>>>(out, sums);
    k_finalize<HID><<<1, 128, 0, stream>>>(sums, bns_g + HID, bns_b + HID, Ws + HID * HID, scsh, shiftW);
    k_gemm<HID, true, false><<<GEMM_B, 256, 0, stream>>>(out, Ws + HID * HID, scsh, shiftW, nullptr, bufA);
    k_agg<false><<<AGG_B, 256, 0, stream>>>(bufA, row_ptr, col, val, dinv, bs + HID, bufB);

    // ---- layer 3: BN(relu(bufB)) -> W3 -> aggregate -> relu -> d_out ----
    hipMemsetAsync(sums, 0, 2 * HID * sizeof(float), stream);
    k_stats<HID, true><<<400, 256, 0, stream>>>(bufB, sums);
    k_finalize<HID><<<1, 128, 0, stream>>>(sums, bns_g + 2 * HID, bns_b + 2 * HID,
                                           Ws + 2 * HID * HID, scsh, shiftW);
    k_gemm<HID, true, false><<<GEMM_B, 256, 0, stream>>>(bufB, Ws + 2 * HID * HID, scsh, shiftW,
                                                         nullptr, bufA);
    k_agg<true><<<AGG_B, 256, 0, stream>>>(bufA, row_ptr, col, val, dinv, bs + 2 * HID, out);
}

// Round 2
// 564.018 us; speedup vs baseline: 1.2896x; 1.2896x over previous
//
#include <hip/hip_runtime.h>

#define N_NODES 100000
#define N_EDGES 1200000
#define IN_F 128
#define HID 64
#define BN_EPS 1e-5f
#define SCAN_NBLK 98   // 98 * 1024 >= 100000

// ---------------- CSR / degree kernels ----------------

__global__ void k_hist(const int* __restrict__ dst, int* __restrict__ cnt) {
    int e = blockIdx.x * 256 + threadIdx.x;
    if (e < N_EDGES) atomicAdd(&cnt[dst[e]], 1);
}

__global__ void k_dinv(const int* __restrict__ cnt, float* __restrict__ dinv) {
    int i = blockIdx.x * 256 + threadIdx.x;
    if (i < N_NODES) dinv[i] = rsqrtf((float)(cnt[i] + 1));  // +1 self loop
}

// block-local exclusive scan: 256 threads x 4 elems = 1024 per block
__global__ void k_scan_block(const int* __restrict__ cnt, int* __restrict__ outv,
                             int* __restrict__ bsum) {
    __shared__ int lds[256];
    int t = threadIdx.x;
    int base = blockIdx.x * 1024 + t * 4;
    int v[4];
#pragma unroll
    for (int q = 0; q < 4; q++) {
        int idx = base + q;
        v[q] = (idx < N_NODES) ? cnt[idx] : 0;
    }
    int tot = v[0] + v[1] + v[2] + v[3];
    lds[t] = tot;
    __syncthreads();
    int x = tot;
    for (int off = 1; off < 256; off <<= 1) {
        int y = (t >= off) ? lds[t - off] : 0;
        __syncthreads();
        x += y;
        lds[t] = x;
        __syncthreads();
    }
    int run = x - tot;  // exclusive prefix of this thread
    if (t == 255) bsum[blockIdx.x] = x;
#pragma unroll
    for (int q = 0; q < 4; q++) {
        int idx = base + q;
        if (idx < N_NODES) outv[idx] = run;
        run += v[q];
    }
}

__global__ void k_scan_bsum(int* bsum, int nb) {
    if (threadIdx.x == 0 && blockIdx.x == 0) {
        int run = 0;
        for (int b = 0; b < nb; b++) { int t = bsum[b]; bsum[b] = run; run += t; }
    }
}

__global__ void k_scan_add(int* __restrict__ row_ptr, const int* __restrict__ bsum,
                           int* __restrict__ cursor) {
    int i = blockIdx.x * 256 + threadIdx.x;
    if (i < N_NODES) {
        int v = row_ptr[i] + bsum[i >> 10];
        row_ptr[i] = v;
        cursor[i] = v;
    }
    if (i == 0) row_ptr[N_NODES] = N_EDGES;
}

__global__ void k_fill(const int* __restrict__ src, const int* __restrict__ dstv,
                       int* __restrict__ cursor, int* __restrict__ col) {
    int e = blockIdx.x * 256 + threadIdx.x;
    if (e < N_EDGES) {
        int pos = atomicAdd(&cursor[dstv[e]], 1);
        col[pos] = src[e];
    }
}

// ---------------- BatchNorm stats ----------------
template <int C, bool RELU>
__global__ void k_stats(const float* __restrict__ h, float* __restrict__ sums) {
    __shared__ float l1[256], l2[256];
    int t = threadIdx.x;
    int c = t & (C - 1);
    const int rpb = 256 / C;
    float s1 = 0.f, s2 = 0.f;
    for (int r = blockIdx.x * rpb + t / C; r < N_NODES; r += gridDim.x * rpb) {
        float v = h[r * C + c];
        if (RELU) v = fmaxf(v, 0.f);
        s1 += v;
        s2 += v * v;
    }
    l1[t] = s1;
    l2[t] = s2;
    __syncthreads();
    if (t < C) {
        for (int r = 1; r < rpb; r++) { s1 += l1[r * C + t]; s2 += l2[r * C + t]; }
        atomicAdd(&sums[t], s1);
        atomicAdd(&sums[C + t], s2);
    }
}

// scale/shift from stats; also shiftW[j] = sum_k shift[k]*W[k][j]
template <int C>
__global__ void k_finalize(const float* __restrict__ sums, const float* __restrict__ gamma,
                           const float* __restrict__ beta, const float* __restrict__ W,
                           float* __restrict__ scaleshift, float* __restrict__ shiftW) {
    __shared__ float sh[C];
    int t = threadIdx.x;  // blockDim = 128
    if (t < C) {
        float m = sums[t] * (1.0f / N_NODES);
        float var = sums[C + t] * (1.0f / N_NODES) - m * m;
        float sc = gamma[t] * rsqrtf(var + BN_EPS);
        float s = beta[t] - m * sc;
        scaleshift[t] = sc;
        scaleshift[C + t] = s;
        sh[t] = s;
    }
    __syncthreads();
    if (t < HID) {
        float acc = 0.f;
#pragma unroll 4
        for (int k = 0; k < C; k++) acc += sh[k] * W[k * HID + t];
        shiftW[t] = acc;
    }
}

// ---------------- fused BN-apply + GEMM ----------------
// out[i][j] = (sum_k g(h[i][k]) * scale[k]*W[k][j] + shiftW[j]) [*dinv[i] | +bias,relu]
template <int K, bool RELU_IN, bool OUT_BIAS_RELU, bool SCALE_DINV>
__global__ __launch_bounds__(256) void k_gemm(const float* __restrict__ h,
                                              const float* __restrict__ W,
                                              const float* __restrict__ scaleshift,
                                              const float* __restrict__ shiftW,
                                              const float* __restrict__ bias,
                                              const float* __restrict__ dinv,
                                              float* __restrict__ out) {
    __shared__ float Wl[K][HID];
    for (int idx = threadIdx.x; idx < K * HID; idx += 256) {
        int k = idx / HID;
        Wl[k][idx % HID] = W[idx] * scaleshift[k];  // fold BN scale into W
    }
    __syncthreads();
    int t = threadIdx.x;
    int row = blockIdx.x * 32 + (t >> 3);  // N_NODES % 32 == 0
    int j0 = (t & 7) * 8;
    const float* hr = h + row * K;
    float acc[8];
#pragma unroll
    for (int jj = 0; jj < 8; jj++) acc[jj] = shiftW[j0 + jj];
    for (int k = 0; k < K; k += 4) {
        float4 a4 = *reinterpret_cast<const float4*>(hr + k);
        float av[4] = {a4.x, a4.y, a4.z, a4.w};
#pragma unroll
        for (int kk = 0; kk < 4; kk++) {
            float v = av[kk];
            if (RELU_IN) v = fmaxf(v, 0.f);
#pragma unroll
            for (int jj = 0; jj < 8; jj++) acc[jj] += v * Wl[k + kk][j0 + jj];
        }
    }
    float di = SCALE_DINV ? dinv[row] : 1.0f;
    float* o = out + row * HID + j0;
    float vv[8];
#pragma unroll
    for (int jj = 0; jj < 8; jj++) {
        float v = acc[jj];
        if (OUT_BIAS_RELU) v = fmaxf(v + bias[j0 + jj], 0.f);
        if (SCALE_DINV) v = v * di;
        vv[jj] = v;
    }
    float4 o0, o1;
    o0.x = vv[0]; o0.y = vv[1]; o0.z = vv[2]; o0.w = vv[3];
    o1.x = vv[4]; o1.y = vv[5]; o1.z = vv[6]; o1.w = vv[7];
    *reinterpret_cast<float4*>(o) = o0;
    *reinterpret_cast<float4*>(o + 4) = o1;
}

// ---------------- per-node gather aggregation ----------------
// t4 rows are pre-scaled by dinv[src]. out[i] = bias + dinv[i]*(t'[i] + sum t'[col[e]])
// Wave = 1 node; 4 groups of 16 lanes, each group gathers one edge row as float4;
// x2 unroll -> 8 gathers in flight. Cross-group shfl_xor reduce at the end.
template <bool RELU_OUT>
__global__ __launch_bounds__(256) void k_agg(const float4* __restrict__ t4,
                                             const int* __restrict__ row_ptr,
                                             const int* __restrict__ col,
                                             const float* __restrict__ dinv,
                                             const float* __restrict__ bias,
                                             float4* __restrict__ out4) {
    int wid = (blockIdx.x * 256 + threadIdx.x) >> 6;
    int lane = threadIdx.x & 63;
    int g = lane >> 4, q = lane & 15;
    if (wid >= N_NODES) return;
    float4 a0 = {0.f, 0.f, 0.f, 0.f}, a1 = {0.f, 0.f, 0.f, 0.f};
    if (g == 0) a1 = t4[(size_t)wid * 16 + q];  // self loop (pre-scaled row)
    int e0 = row_ptr[wid], e1 = row_ptr[wid + 1];
    int e = e0;
    for (; e + 8 <= e1; e += 8) {
        int s0 = col[e + g];
        int s1 = col[e + 4 + g];
        float4 v0 = t4[(size_t)s0 * 16 + q];
        float4 v1 = t4[(size_t)s1 * 16 + q];
        a0.x += v0.x; a0.y += v0.y; a0.z += v0.z; a0.w += v0.w;
        a1.x += v1.x; a1.y += v1.y; a1.z += v1.z; a1.w += v1.w;
    }
    for (; e < e1; e += 4) {
        if (e + g < e1) {
            int s = col[e + g];
            float4 v = t4[(size_t)s * 16 + q];
            a0.x += v.x; a0.y += v.y; a0.z += v.z; a0.w += v.w;
        }
    }
    float4 a;
    a.x = a0.x + a1.x; a.y = a0.y + a1.y; a.z = a0.z + a1.z; a.w = a0.w + a1.w;
    a.x += __shfl_xor(a.x, 16); a.y += __shfl_xor(a.y, 16);
    a.z += __shfl_xor(a.z, 16); a.w += __shfl_xor(a.w, 16);
    a.x += __shfl_xor(a.x, 32); a.y += __shfl_xor(a.y, 32);
    a.z += __shfl_xor(a.z, 32); a.w += __shfl_xor(a.w, 32);
    if (g == 0) {
        float di = dinv[wid];
        float4 b = reinterpret_cast<const float4*>(bias)[q];
        float4 o;
        o.x = di * a.x + b.x; o.y = di * a.y + b.y;
        o.z = di * a.z + b.z; o.w = di * a.w + b.w;
        if (RELU_OUT) {
            o.x = fmaxf(o.x, 0.f); o.y = fmaxf(o.y, 0.f);
            o.z = fmaxf(o.z, 0.f); o.w = fmaxf(o.w, 0.f);
        }
        out4[(size_t)wid * 16 + q] = o;
    }
}

// ---------------- launch ----------------

extern "C" void kernel_launch(void* const* d_in, const int* in_sizes, int n_in,
                              void* d_out, int out_size, void* d_ws, size_t ws_size,
                              hipStream_t stream) {
    const float* x = (const float*)d_in[0];
    const int* ei = (const int*)d_in[1];
    const int* src = ei;
    const int* dst = ei + N_EDGES;
    const float* bn0_g = (const float*)d_in[2];
    const float* bn0_b = (const float*)d_in[3];
    const float* W0 = (const float*)d_in[4];
    const float* b0 = (const float*)d_in[5];
    const float* bns_g = (const float*)d_in[6];
    const float* bns_b = (const float*)d_in[7];
    const float* Ws = (const float*)d_in[8];
    const float* bs = (const float*)d_in[9];
    float* out = (float*)d_out;
    char* ws = (char*)d_ws;

    // workspace layout (bytes)
    float* dinv    = (float*)(ws + 0);          //  400,000
    int*   cnt     = (int*)(ws + 400128);       //  400,000
    int*   row_ptr = (int*)(ws + 800256);       //  400,004
    int*   cursor  = (int*)(ws + 1200384);      //  400,000
    int*   col     = (int*)(ws + 1600512);      // 4,800,000
    int*   bsum    = (int*)(ws + 6400512);      //      392
    float* sums    = (float*)(ws + 6401024);    //    2,560 (4 regions)
    float* scsh    = (float*)(ws + 6403584);    //    1,024
    float* shiftW  = (float*)(ws + 6404608);    //      256
    float* bufA    = (float*)(ws + 6405120);    // 25,600,000
    float* bufB    = (float*)(ws + 32005120);   // 25,600,000 -> 57,605,120 total
    float* sums0 = sums;          // 256 floats (IN_F)
    float* sums1 = sums + 256;    // 128 floats
    float* sums2 = sums + 384;    // 128
    float* sums3 = sums + 512;    // 128

    const int EB = (N_EDGES + 255) / 256;
    const int NB = (N_NODES + 255) / 256;
    const int GEMM_B = N_NODES / 32;        // 3125
    const int AGG_B = (N_NODES + 3) / 4;    // 25000 (4 waves/block)

    // ---- CSR build (layer-invariant) + zero all stat accumulators ----
    hipMemsetAsync(cnt, 0, N_NODES * sizeof(int), stream);
    hipMemsetAsync(sums, 0, 640 * sizeof(float), stream);
    k_hist<<<EB, 256, 0, stream>>>(dst, cnt);
    k_dinv<<<NB, 256, 0, stream>>>(cnt, dinv);
    k_scan_block<<<SCAN_NBLK, 256, 0, stream>>>(cnt, row_ptr, bsum);
    k_scan_bsum<<<1, 64, 0, stream>>>(bsum, SCAN_NBLK);
    k_scan_add<<<NB, 256, 0, stream>>>(row_ptr, bsum, cursor);
    k_fill<<<EB, 256, 0, stream>>>(src, dst, cursor, col);

    // ---- layer 0: BN(x) -> Linear -> ReLU -> bufA ----
    k_stats<IN_F, false><<<400, 256, 0, stream>>>(x, sums0);
    k_finalize<IN_F><<<1, 128, 0, stream>>>(sums0, bn0_g, bn0_b, W0, scsh, shiftW);
    k_gemm<IN_F, false, true, false><<<GEMM_B, 256, 0, stream>>>(x, W0, scsh, shiftW, b0,
                                                                 nullptr, bufA);

    // ---- layer 1: BN(bufA) -> W1 (row-scaled by dinv) -> aggregate -> d_out ----
    k_stats<HID, false><<<400, 256, 0, stream>>>(bufA, sums1);
    k_finalize<HID><<<1, 128, 0, stream>>>(sums1, bns_g, bns_b, Ws, scsh, shiftW);
    k_gemm<HID, false, false, true><<<GEMM_B, 256, 0, stream>>>(bufA, Ws, scsh, shiftW, nullptr,
                                                                dinv, bufB);
    k_agg<false><<<AGG_B, 256, 0, stream>>>((const float4*)bufB, row_ptr, col, dinv, bs,
                                            (float4*)out);

    // ---- layer 2 ----
    k_stats<HID, true><<<400, 256, 0, stream>>>(out, sums2);
    k_finalize<HID><<<1, 128, 0, stream>>>(sums2, bns_g + HID, bns_b + HID, Ws + HID * HID,
                                           scsh, shiftW);
    k_gemm<HID, true, false, true><<<GEMM_B, 256, 0, stream>>>(out, Ws + HID * HID, scsh, shiftW,
                                                               nullptr, dinv, bufA);
    k_agg<false><<<AGG_B, 256, 0, stream>>>((const float4*)bufA, row_ptr, col, dinv, bs + HID,
                                            (float4*)bufB);

    // ---- layer 3 ----
    k_stats<HID, true><<<400, 256, 0, stream>>>(bufB, sums3);
    k_finalize<HID><<<1, 128, 0, stream>>>(sums3, bns_g + 2 * HID, bns_b + 2 * HID,
                                           Ws + 2 * HID * HID, scsh, shiftW);
    k_gemm<HID, true, false, true><<<GEMM_B, 256, 0, stream>>>(bufB, Ws + 2 * HID * HID, scsh,
                                                               shiftW, nullptr, dinv, bufA);
    k_agg<true><<<AGG_B, 256, 0, stream>>>((const float4*)bufA, row_ptr, col, dinv,
                                           bs + 2 * HID, (float4*)out);
}

// Round 3
// 477.212 us; speedup vs baseline: 1.5242x; 1.1819x over previous
//
#include <hip/hip_runtime.h>

#define N_NODES 100000
#define N_EDGES 1200000
#define IN_F 128
#define HID 64
#define BN_EPS 1e-5f
#define SCAN_NBLK 98   // 98 * 1024 >= 100000
#define E4 (N_EDGES / 4)

typedef unsigned int uint;
typedef unsigned short ushort;

__device__ inline uint f2bf(float f) {        // f32 -> bf16 (RNE), returns low 16 bits
    uint u = __float_as_uint(f);
    return (u + 0x7fffu + ((u >> 16) & 1u)) >> 16;
}
__device__ inline float bflo(uint v) { return __uint_as_float(v << 16); }
__device__ inline float bfhi(uint v) { return __uint_as_float(v & 0xffff0000u); }

// ---------------- CSR build ----------------
// pass 1: per-dst histogram + per-edge rank (position within its dst bucket)
__global__ void k_hist_rank(const int4* __restrict__ dst4, int* __restrict__ cnt,
                            int4* __restrict__ rank4) {
    int i = blockIdx.x * 256 + threadIdx.x;
    if (i < E4) {
        int4 d = dst4[i];
        int4 r;
        r.x = atomicAdd(&cnt[d.x], 1);
        r.y = atomicAdd(&cnt[d.y], 1);
        r.z = atomicAdd(&cnt[d.z], 1);
        r.w = atomicAdd(&cnt[d.w], 1);
        rank4[i] = r;
    }
}

// block-local exclusive scan (256 thr x 4) + dinv computation folded in
__global__ void k_scan_block(const int* __restrict__ cnt, int* __restrict__ outv,
                             int* __restrict__ bsum, float* __restrict__ dinv) {
    __shared__ int lds[256];
    int t = threadIdx.x;
    int base = blockIdx.x * 1024 + t * 4;
    int v[4];
#pragma unroll
    for (int q = 0; q < 4; q++) {
        int idx = base + q;
        v[q] = (idx < N_NODES) ? cnt[idx] : 0;
        if (idx < N_NODES) dinv[idx] = rsqrtf((float)(v[q] + 1));  // +1 self loop
    }
    int tot = v[0] + v[1] + v[2] + v[3];
    lds[t] = tot;
    __syncthreads();
    int x = tot;
    for (int off = 1; off < 256; off <<= 1) {
        int y = (t >= off) ? lds[t - off] : 0;
        __syncthreads();
        x += y;
        lds[t] = x;
        __syncthreads();
    }
    int run = x - tot;
    if (t == 255) bsum[blockIdx.x] = x;
#pragma unroll
    for (int q = 0; q < 4; q++) {
        int idx = base + q;
        if (idx < N_NODES) outv[idx] = run;
        run += v[q];
    }
}

__global__ void k_scan_bsum(int* bsum, int nb) {
    if (threadIdx.x == 0 && blockIdx.x == 0) {
        int run = 0;
        for (int b = 0; b < nb; b++) { int t = bsum[b]; bsum[b] = run; run += t; }
    }
}

__global__ void k_scan_add(int* __restrict__ row_ptr, const int* __restrict__ bsum) {
    int i = blockIdx.x * 256 + threadIdx.x;
    if (i < N_NODES) row_ptr[i] += bsum[i >> 10];
    if (i == 0) row_ptr[N_NODES] = N_EDGES;
}

// pass 2: place edges — no atomics, 4 edges/thread for ILP
__global__ void k_fill(const int4* __restrict__ src4, const int4* __restrict__ dst4,
                       const int4* __restrict__ rank4, const int* __restrict__ row_ptr,
                       int* __restrict__ col) {
    int i = blockIdx.x * 256 + threadIdx.x;
    if (i < E4) {
        int4 s = src4[i];
        int4 d = dst4[i];
        int4 r = rank4[i];
        int p0 = row_ptr[d.x] + r.x;
        int p1 = row_ptr[d.y] + r.y;
        int p2 = row_ptr[d.z] + r.z;
        int p3 = row_ptr[d.w] + r.w;
        col[p0] = s.x;
        col[p1] = s.y;
        col[p2] = s.z;
        col[p3] = s.w;
    }
}

// ---------------- BatchNorm stats (column sum + sumsq) ----------------
template <int C, bool RELU>
__global__ void k_stats(const float* __restrict__ h, float* __restrict__ sums) {
    __shared__ float l1[256], l2[256];
    int t = threadIdx.x;
    int c = t & (C - 1);
    const int rpb = 256 / C;
    float s1 = 0.f, s2 = 0.f;
    for (int r = blockIdx.x * rpb + t / C; r < N_NODES; r += gridDim.x * rpb) {
        float v = h[(size_t)r * C + c];
        if (RELU) v = fmaxf(v, 0.f);
        s1 += v;
        s2 += v * v;
    }
    l1[t] = s1;
    l2[t] = s2;
    __syncthreads();
    if (t < C) {
        for (int r = 1; r < rpb; r++) { s1 += l1[r * C + t]; s2 += l2[r * C + t]; }
        atomicAdd(&sums[t], s1);
        atomicAdd(&sums[C + t], s2);
    }
}

// ---------------- fused BN-finalize + BN-apply + GEMM ----------------
// BF16_OUT_DINV=false: out f32 = relu(BN(h)@W + bias)      (layer 0)
// BF16_OUT_DINV=true : out bf16 = (BN(relu?(h))@W) * dinv[row]   (t matrix)
template <int K, bool RELU_IN, bool BF16_OUT_DINV>
__global__ __launch_bounds__(256) void k_gemm(const float* __restrict__ h,
                                              const float* __restrict__ W,
                                              const float* __restrict__ sums,
                                              const float* __restrict__ gamma,
                                              const float* __restrict__ beta,
                                              const float* __restrict__ bias,
                                              const float* __restrict__ dinv,
                                              void* __restrict__ outp) {
    __shared__ float Wl[K][HID];
    __shared__ float shW[HID];
    __shared__ float scale_s[K], shift_s[K];
    int t = threadIdx.x;
    if (t < K) {
        float m = sums[t] * (1.0f / N_NODES);
        float var = sums[K + t] * (1.0f / N_NODES) - m * m;
        float sc = gamma[t] * rsqrtf(var + BN_EPS);
        scale_s[t] = sc;
        shift_s[t] = beta[t] - m * sc;
    }
    __syncthreads();
    for (int idx = t; idx < K * HID; idx += 256) {
        int k = idx >> 6;
        Wl[k][idx & 63] = W[idx] * scale_s[k];
    }
    if (t < HID) {
        float acc = 0.f;
#pragma unroll 4
        for (int k = 0; k < K; k++) acc += shift_s[k] * W[k * HID + t];
        shW[t] = acc;
    }
    __syncthreads();

    int row = blockIdx.x * 32 + (t >> 3);  // N_NODES % 32 == 0
    int j0 = (t & 7) * 8;
    const float* hr = h + (size_t)row * K;
    float acc[8];
#pragma unroll
    for (int jj = 0; jj < 8; jj++) acc[jj] = shW[j0 + jj];
    for (int k = 0; k < K; k += 4) {
        float4 a4 = *reinterpret_cast<const float4*>(hr + k);
        float av[4] = {a4.x, a4.y, a4.z, a4.w};
#pragma unroll
        for (int kk = 0; kk < 4; kk++) {
            float v = av[kk];
            if (RELU_IN) v = fmaxf(v, 0.f);
#pragma unroll
            for (int jj = 0; jj < 8; jj++) acc[jj] += v * Wl[k + kk][j0 + jj];
        }
    }
    if (BF16_OUT_DINV) {
        float di = dinv[row];
        uint4 o;
        o.x = f2bf(acc[0] * di) | (f2bf(acc[1] * di) << 16);
        o.y = f2bf(acc[2] * di) | (f2bf(acc[3] * di) << 16);
        o.z = f2bf(acc[4] * di) | (f2bf(acc[5] * di) << 16);
        o.w = f2bf(acc[6] * di) | (f2bf(acc[7] * di) << 16);
        reinterpret_cast<uint4*>(outp)[(size_t)row * 8 + (t & 7)] = o;
    } else {
        float vv[8];
#pragma unroll
        for (int jj = 0; jj < 8; jj++) vv[jj] = fmaxf(acc[jj] + bias[j0 + jj], 0.f);
        float* o = (float*)outp + (size_t)row * HID + j0;
        float4 o0{vv[0], vv[1], vv[2], vv[3]};
        float4 o1{vv[4], vv[5], vv[6], vv[7]};
        *reinterpret_cast<float4*>(o) = o0;
        *reinterpret_cast<float4*>(o + 4) = o1;
    }
}

// ---------------- per-node gather aggregation (bf16 rows) ----------------
// t rows pre-scaled by dinv[src]; out[i] = bias + dinv[i]*(t'[i] + sum t'[col[e]])
// Wave = 1 node; 8 groups of 8 lanes, each group gathers one edge row (8 x 16B).
template <bool RELU_OUT>
__global__ __launch_bounds__(256) void k_agg(const uint4* __restrict__ t4,
                                             const int* __restrict__ row_ptr,
                                             const int* __restrict__ col,
                                             const float* __restrict__ dinv,
                                             const float* __restrict__ bias,
                                             float* __restrict__ out) {
    int wid = (blockIdx.x * 256 + threadIdx.x) >> 6;
    int lane = threadIdx.x & 63;
    int g = lane >> 3, q = lane & 7;
    if (wid >= N_NODES) return;
    float a[8] = {0.f, 0.f, 0.f, 0.f, 0.f, 0.f, 0.f, 0.f};
    int e0 = row_ptr[wid], e1 = row_ptr[wid + 1];
    uint4 selfv = {0, 0, 0, 0};
    if (g == 0) selfv = t4[(size_t)wid * 8 + q];
    for (int base = e0; base < e1; base += 8) {
        int ee = base + g;
        if (ee < e1) {
            int s = col[ee];
            uint4 v = t4[(size_t)s * 8 + q];
            a[0] += bflo(v.x); a[1] += bfhi(v.x);
            a[2] += bflo(v.y); a[3] += bfhi(v.y);
            a[4] += bflo(v.z); a[5] += bfhi(v.z);
            a[6] += bflo(v.w); a[7] += bfhi(v.w);
        }
    }
    if (g == 0) {
        a[0] += bflo(selfv.x); a[1] += bfhi(selfv.x);
        a[2] += bflo(selfv.y); a[3] += bfhi(selfv.y);
        a[4] += bflo(selfv.z); a[5] += bfhi(selfv.z);
        a[6] += bflo(selfv.w); a[7] += bfhi(selfv.w);
    }
#pragma unroll
    for (int off = 8; off <= 32; off <<= 1) {
#pragma unroll
        for (int j = 0; j < 8; j++) a[j] += __shfl_xor(a[j], off);
    }
    if (g == 0) {
        float di = dinv[wid];
        float4 b0v = reinterpret_cast<const float4*>(bias)[q * 2];
        float4 b1v = reinterpret_cast<const float4*>(bias)[q * 2 + 1];
        float4 o0{di * a[0] + b0v.x, di * a[1] + b0v.y, di * a[2] + b0v.z, di * a[3] + b0v.w};
        float4 o1{di * a[4] + b1v.x, di * a[5] + b1v.y, di * a[6] + b1v.z, di * a[7] + b1v.w};
        if (RELU_OUT) {
            o0.x = fmaxf(o0.x, 0.f); o0.y = fmaxf(o0.y, 0.f);
            o0.z = fmaxf(o0.z, 0.f); o0.w = fmaxf(o0.w, 0.f);
            o1.x = fmaxf(o1.x, 0.f); o1.y = fmaxf(o1.y, 0.f);
            o1.z = fmaxf(o1.z, 0.f); o1.w = fmaxf(o1.w, 0.f);
        }
        float4* orow = reinterpret_cast<float4*>(out + (size_t)wid * HID + q * 8);
        orow[0] = o0;
        orow[1] = o1;
    }
}

// ---------------- launch ----------------

extern "C" void kernel_launch(void* const* d_in, const int* in_sizes, int n_in,
                              void* d_out, int out_size, void* d_ws, size_t ws_size,
                              hipStream_t stream) {
    const float* x = (const float*)d_in[0];
    const int* ei = (const int*)d_in[1];
    const int4* src4 = (const int4*)ei;
    const int4* dst4 = (const int4*)(ei + N_EDGES);
    const float* bn0_g = (const float*)d_in[2];
    const float* bn0_b = (const float*)d_in[3];
    const float* W0 = (const float*)d_in[4];
    const float* b0 = (const float*)d_in[5];
    const float* bns_g = (const float*)d_in[6];
    const float* bns_b = (const float*)d_in[7];
    const float* Ws = (const float*)d_in[8];
    const float* bs = (const float*)d_in[9];
    float* out = (float*)d_out;
    char* ws = (char*)d_ws;

    // workspace layout (bytes)
    float* dinv    = (float*)(ws + 0);          //   400,128
    int*   cnt     = (int*)(ws + 400128);       //   400,128
    int*   row_ptr = (int*)(ws + 800256);       //   400,384 (N+1)
    int*   rank    = (int*)(ws + 1200640);      // 4,800,000
    int*   col     = (int*)(ws + 6000640);      // 4,800,000
    int*   bsum    = (int*)(ws + 10800640);     //       512
    float* sums    = (float*)(ws + 10801152);   //     2,560
    void*  tbuf    = (void*)(ws + 10803712);    // 12,800,000 (bf16 t matrix)
    float* bufA    = (float*)(ws + 23603712);   // 25,600,000 -> 49.2 MB total
    float* sums0 = sums;          // 256 floats (IN_F)
    float* sums1 = sums + 256;    // 128 floats
    float* sums2 = sums + 384;
    float* sums3 = sums + 512;

    const int EB4 = (E4 + 255) / 256;       // 1172
    const int NB = (N_NODES + 255) / 256;
    const int GEMM_B = N_NODES / 32;        // 3125
    const int AGG_B = (N_NODES + 3) / 4;    // 25000

    // ---- CSR build (layer-invariant) ----
    hipMemsetAsync(cnt, 0, N_NODES * sizeof(int), stream);
    hipMemsetAsync(sums, 0, 640 * sizeof(float), stream);
    k_hist_rank<<<EB4, 256, 0, stream>>>(dst4, cnt, (int4*)rank);
    k_scan_block<<<SCAN_NBLK, 256, 0, stream>>>(cnt, row_ptr, bsum, dinv);
    k_scan_bsum<<<1, 64, 0, stream>>>(bsum, SCAN_NBLK);
    k_scan_add<<<NB, 256, 0, stream>>>(row_ptr, bsum);
    k_fill<<<EB4, 256, 0, stream>>>(src4, dst4, (const int4*)rank, row_ptr, col);

    // ---- layer 0: BN(x) -> Linear -> ReLU -> bufA (f32 h0) ----
    k_stats<IN_F, false><<<400, 256, 0, stream>>>(x, sums0);
    k_gemm<IN_F, false, false><<<GEMM_B, 256, 0, stream>>>(x, W0, sums0, bn0_g, bn0_b, b0,
                                                           nullptr, bufA);

    // ---- layer 1: BN(h0) -> W1 -> *dinv -> bf16 t -> aggregate -> d_out (pre-relu h1) ----
    k_stats<HID, false><<<400, 256, 0, stream>>>(bufA, sums1);
    k_gemm<HID, false, true><<<GEMM_B, 256, 0, stream>>>(bufA, Ws, sums1, bns_g, bns_b, nullptr,
                                                         dinv, tbuf);
    k_agg<false><<<AGG_B, 256, 0, stream>>>((const uint4*)tbuf, row_ptr, col, dinv, bs, out);

    // ---- layer 2: h1 in d_out -> bufA (pre-relu h2) ----
    k_stats<HID, true><<<400, 256, 0, stream>>>(out, sums2);
    k_gemm<HID, true, true><<<GEMM_B, 256, 0, stream>>>(out, Ws + HID * HID, sums2, bns_g + HID,
                                                        bns_b + HID, nullptr, dinv, tbuf);
    k_agg<false><<<AGG_B, 256, 0, stream>>>((const uint4*)tbuf, row_ptr, col, dinv, bs + HID,
                                            bufA);

    // ---- layer 3: h2 in bufA -> d_out (relu) ----
    k_stats<HID, true><<<400, 256, 0, stream>>>(bufA, sums3);
    k_gemm<HID, true, true><<<GEMM_B, 256, 0, stream>>>(bufA, Ws + 2 * HID * HID, sums3,
                                                        bns_g + 2 * HID, bns_b + 2 * HID,
                                                        nullptr, dinv, tbuf);
    k_agg<true><<<AGG_B, 256, 0, stream>>>((const uint4*)tbuf, row_ptr, col, dinv,
                                           bs + 2 * HID, out);
}

// Round 4
// 351.449 us; speedup vs baseline: 2.0696x; 1.3578x over previous
//
#include <hip/hip_runtime.h>

#define N_NODES 100000
#define N_EDGES 1200000
#define IN_F 128
#define HID 64
#define BN_EPS 1e-5f
#define SCAN_NBLK 98   // 98 * 1024 >= 100000
#define E4 (N_EDGES / 4)

typedef unsigned int uint;
typedef unsigned short ushort;
typedef __attribute__((ext_vector_type(8))) short bf16x8;
typedef __attribute__((ext_vector_type(4))) float f32x4;

__device__ inline uint f2bf(float f) {        // f32 -> bf16 (RNE), low 16 bits
    uint u = __float_as_uint(f);
    return (u + 0x7fffu + ((u >> 16) & 1u)) >> 16;
}
__device__ inline float bflo(uint v) { return __uint_as_float(v << 16); }
__device__ inline float bfhi(uint v) { return __uint_as_float(v & 0xffff0000u); }

// ---------------- CSR build ----------------
__global__ void k_hist_rank(const int4* __restrict__ dst4, int* __restrict__ cnt,
                            int4* __restrict__ rank4) {
    int i = blockIdx.x * 256 + threadIdx.x;
    if (i < E4) {
        int4 d = dst4[i];
        int4 r;
        r.x = atomicAdd(&cnt[d.x], 1);
        r.y = atomicAdd(&cnt[d.y], 1);
        r.z = atomicAdd(&cnt[d.z], 1);
        r.w = atomicAdd(&cnt[d.w], 1);
        rank4[i] = r;
    }
}

__global__ void k_scan_block(const int* __restrict__ cnt, int* __restrict__ outv,
                             int* __restrict__ bsum, float* __restrict__ dinv) {
    __shared__ int lds[256];
    int t = threadIdx.x;
    int base = blockIdx.x * 1024 + t * 4;
    int v[4];
#pragma unroll
    for (int q = 0; q < 4; q++) {
        int idx = base + q;
        v[q] = (idx < N_NODES) ? cnt[idx] : 0;
        if (idx < N_NODES) dinv[idx] = rsqrtf((float)(v[q] + 1));
    }
    int tot = v[0] + v[1] + v[2] + v[3];
    lds[t] = tot;
    __syncthreads();
    int x = tot;
    for (int off = 1; off < 256; off <<= 1) {
        int y = (t >= off) ? lds[t - off] : 0;
        __syncthreads();
        x += y;
        lds[t] = x;
        __syncthreads();
    }
    int run = x - tot;
    if (t == 255) bsum[blockIdx.x] = x;
#pragma unroll
    for (int q = 0; q < 4; q++) {
        int idx = base + q;
        if (idx < N_NODES) outv[idx] = run;
        run += v[q];
    }
}

__global__ void k_scan_bsum(int* bsum, int nb) {
    if (threadIdx.x == 0 && blockIdx.x == 0) {
        int run = 0;
        for (int b = 0; b < nb; b++) { int t = bsum[b]; bsum[b] = run; run += t; }
    }
}

__global__ void k_scan_add(int* __restrict__ row_ptr, const int* __restrict__ bsum) {
    int i = blockIdx.x * 256 + threadIdx.x;
    if (i < N_NODES) row_ptr[i] += bsum[i >> 10];
    if (i == 0) row_ptr[N_NODES] = N_EDGES;
}

__global__ void k_fill(const int4* __restrict__ src4, const int4* __restrict__ dst4,
                       const int4* __restrict__ rank4, const int* __restrict__ row_ptr,
                       int* __restrict__ col) {
    int i = blockIdx.x * 256 + threadIdx.x;
    if (i < E4) {
        int4 s = src4[i];
        int4 d = dst4[i];
        int4 r = rank4[i];
        col[row_ptr[d.x] + r.x] = s.x;
        col[row_ptr[d.y] + r.y] = s.y;
        col[row_ptr[d.z] + r.z] = s.z;
        col[row_ptr[d.w] + r.w] = s.w;
    }
}

// ---------------- stats on f32 x (C=128) + bf16 conversion ----------------
__global__ __launch_bounds__(256) void k_stats_in(const float4* __restrict__ x4,
                                                  uint2* __restrict__ xb,
                                                  float* __restrict__ sums) {
    __shared__ float lds[4][32][8];
    int t = threadIdx.x;
    int cq = t & 31, rs = t >> 5;
    float s1[4] = {0.f, 0.f, 0.f, 0.f}, s2[4] = {0.f, 0.f, 0.f, 0.f};
    for (int r = blockIdx.x * 8 + rs; r < N_NODES; r += gridDim.x * 8) {
        float4 v = x4[(size_t)r * 32 + cq];
        s1[0] += v.x; s2[0] += v.x * v.x;
        s1[1] += v.y; s2[1] += v.y * v.y;
        s1[2] += v.z; s2[2] += v.z * v.z;
        s1[3] += v.w; s2[3] += v.w * v.w;
        uint2 p;
        p.x = f2bf(v.x) | (f2bf(v.y) << 16);
        p.y = f2bf(v.z) | (f2bf(v.w) << 16);
        xb[(size_t)r * 32 + cq] = p;
    }
#pragma unroll
    for (int j = 0; j < 4; j++) {
        s1[j] += __shfl_xor(s1[j], 32);
        s2[j] += __shfl_xor(s2[j], 32);
    }
    int w = t >> 6;
    if ((t & 63) < 32) {
#pragma unroll
        for (int j = 0; j < 4; j++) {
            lds[w][cq][j] = s1[j];
            lds[w][cq][4 + j] = s2[j];
        }
    }
    __syncthreads();
    {
        int cq2 = t >> 3, k = t & 7;
        float v = lds[0][cq2][k] + lds[1][cq2][k] + lds[2][cq2][k] + lds[3][cq2][k];
        int col = cq2 * 4 + (k & 3);
        atomicAdd(&sums[(k >> 2) * 128 + col], v);
    }
}

// ---------------- stats on bf16 h (C=64, post-relu rows) ----------------
__global__ __launch_bounds__(256) void k_stats_h(const uint4* __restrict__ h4,
                                                 float* __restrict__ sums) {
    __shared__ float lds[4][8][16];
    int t = threadIdx.x;
    int cg = t & 7, rs = t >> 3;
    float s1[8], s2[8];
#pragma unroll
    for (int j = 0; j < 8; j++) { s1[j] = 0.f; s2[j] = 0.f; }
    for (int r = blockIdx.x * 32 + rs; r < N_NODES; r += gridDim.x * 32) {
        uint4 v = h4[(size_t)r * 8 + cg];
        float f;
        f = bflo(v.x); s1[0] += f; s2[0] += f * f;
        f = bfhi(v.x); s1[1] += f; s2[1] += f * f;
        f = bflo(v.y); s1[2] += f; s2[2] += f * f;
        f = bfhi(v.y); s1[3] += f; s2[3] += f * f;
        f = bflo(v.z); s1[4] += f; s2[4] += f * f;
        f = bfhi(v.z); s1[5] += f; s2[5] += f * f;
        f = bflo(v.w); s1[6] += f; s2[6] += f * f;
        f = bfhi(v.w); s1[7] += f; s2[7] += f * f;
    }
#pragma unroll
    for (int off = 8; off <= 32; off <<= 1) {
#pragma unroll
        for (int j = 0; j < 8; j++) {
            s1[j] += __shfl_xor(s1[j], off);
            s2[j] += __shfl_xor(s2[j], off);
        }
    }
    int w = t >> 6;
    if ((t & 63) < 8) {
#pragma unroll
        for (int j = 0; j < 8; j++) {
            lds[w][cg][j] = s1[j];
            lds[w][cg][8 + j] = s2[j];
        }
    }
    __syncthreads();
    if (t < 128) {
        int cg2 = t >> 4, k = t & 15;
        float v = lds[0][cg2][k] + lds[1][cg2][k] + lds[2][cg2][k] + lds[3][cg2][k];
        int col = cg2 * 8 + (k & 7);
        atomicAdd(&sums[(k >> 3) * 64 + col], v);
    }
}

// ---------------- MFMA GEMM: BN-finalize + BN-apply + matmul + epilogue ----------------
// A = h bf16 [N][K] (post-relu already), Wl = scale*W bf16, acc init = shiftW.
// LAYER0: out = relu(acc + bias) bf16.  else: out = acc * dinv[row] bf16 (t matrix).
template <int K, bool LAYER0>
__global__ __launch_bounds__(256) void k_gemm_mfma(
    const ushort* __restrict__ h, const float* __restrict__ W,
    const float* __restrict__ sums, const float* __restrict__ gamma,
    const float* __restrict__ beta, const float* __restrict__ bias,
    const float* __restrict__ dinv, ushort* __restrict__ out) {
    __shared__ ushort Alds[64 * K];   // [64 rows][K], swizzled
    __shared__ ushort Wt[64 * K];     // [n][k] transposed, swizzled
    __shared__ float scale_s[K], shift_s[K], shW[HID];
    const int KB = K * 2;             // LDS row stride bytes
    int t = threadIdx.x;
    if (t < K) {
        float m = sums[t] * (1.0f / N_NODES);
        float var = sums[K + t] * (1.0f / N_NODES) - m * m;
        float sc = gamma[t] * rsqrtf(var + BN_EPS);
        scale_s[t] = sc;
        shift_s[t] = beta[t] - m * sc;
    }
    __syncthreads();
    // stage Wt = (scale*W)^T as bf16, swizzled
    for (int idx = t; idx < K * 64; idx += 256) {
        int k = idx >> 6, n = idx & 63;
        float v = W[idx] * scale_s[k];
        int byte = n * KB + k * 2;
        byte ^= ((n & 7) << 4);
        *(ushort*)((char*)Wt + byte) = (ushort)f2bf(v);
    }
    // shW[n] = sum_k shift[k] * W[k][n]
    if (t < HID) {
        float acc = 0.f;
#pragma unroll 4
        for (int k = 0; k < K; k++) acc += shift_s[k] * W[k * HID + t];
        shW[t] = acc;
    }
    // stage A tile (64 rows), swizzled
    int row0 = blockIdx.x * 64;
    {
        const int KG = K / 8;
        for (int idx = t; idx < 64 * KG; idx += 256) {
            int r = idx / KG, kg = idx % KG;
            int rr = row0 + r;
            if (rr >= N_NODES) rr = N_NODES - 1;
            uint4 v = *(const uint4*)(h + (size_t)rr * K + kg * 8);
            int byte = r * KB + kg * 16;
            byte ^= ((r & 7) << 4);
            *(uint4*)((char*)Alds + byte) = v;
        }
    }
    __syncthreads();

    int w = t >> 6, l = t & 63;
    int lr = l & 15, lg = l >> 4;
    f32x4 acc[4];
#pragma unroll
    for (int nt = 0; nt < 4; nt++) {
        float s = shW[nt * 16 + lr];
        acc[nt] = (f32x4){s, s, s, s};
    }
#pragma unroll
    for (int c = 0; c < K / 32; c++) {
        int arow = w * 16 + lr;
        int abyte = (arow * KB + c * 64 + lg * 16) ^ ((arow & 7) << 4);
        bf16x8 a = *(const bf16x8*)((const char*)Alds + abyte);
#pragma unroll
        for (int nt = 0; nt < 4; nt++) {
            int n = nt * 16 + lr;
            int bbyte = (n * KB + c * 64 + lg * 16) ^ ((n & 7) << 4);
            bf16x8 b = *(const bf16x8*)((const char*)Wt + bbyte);
            acc[nt] = __builtin_amdgcn_mfma_f32_16x16x32_bf16(a, b, acc[nt], 0, 0, 0);
        }
    }
    // epilogue: repack through wave-private A region -> coalesced stores
    int wrow0 = row0 + w * 16;
    char* myA = (char*)Alds + w * 16 * KB;   // >= 2KB available
    float4 dv;
    float bias_v[4];
    if (LAYER0) {
#pragma unroll
        for (int nt = 0; nt < 4; nt++) bias_v[nt] = bias[nt * 16 + lr];
    } else {
        int dbase = wrow0 + lg * 4;
        if (dbase > N_NODES - 4) dbase = N_NODES - 4;
        dv = *(const float4*)(dinv + dbase);
    }
    float dvv[4] = {dv.x, dv.y, dv.z, dv.w};
#pragma unroll
    for (int nt = 0; nt < 4; nt++) {
#pragma unroll
        for (int r = 0; r < 4; r++) {
            float v = acc[nt][r];
            if (LAYER0) v = fmaxf(v + bias_v[nt], 0.f);
            else v = v * dvv[r];
            int rowl = lg * 4 + r;
            int byte = (rowl * 128 + (nt * 16 + lr) * 2) ^ ((rowl & 7) << 4);
            *(ushort*)(myA + byte) = (ushort)f2bf(v);
        }
    }
    // read back rows (16 rows x 128B = 2KB), coalesced global store
    {
        int rowl0 = l >> 3, kg0 = l & 7;
        int b0 = (rowl0 * 128 + kg0 * 16) ^ ((rowl0 & 7) << 4);
        int rowl1 = 8 + (l >> 3);
        int b1 = (rowl1 * 128 + kg0 * 16) ^ ((rowl1 & 7) << 4);
        uint4 v0 = *(uint4*)(myA + b0);
        uint4 v1 = *(uint4*)(myA + b1);
        size_t g = (size_t)wrow0 * 128 + l * 16;
        if (wrow0 + rowl0 < N_NODES) *(uint4*)((char*)out + g) = v0;
        if (wrow0 + rowl1 < N_NODES) *(uint4*)((char*)out + g + 1024) = v1;
    }
}

// ---------------- per-node gather aggregation (bf16 rows) ----------------
// out[i] = relu(bias + dinv[i]*(t'[i] + sum t'[col[e]])); OUT_BF16 picks dtype.
template <bool OUT_BF16>
__global__ __launch_bounds__(256) void k_agg(const uint4* __restrict__ t4,
                                             const int* __restrict__ row_ptr,
                                             const int* __restrict__ col,
                                             const float* __restrict__ dinv,
                                             const float* __restrict__ bias,
                                             void* __restrict__ out) {
    int wid = (blockIdx.x * 256 + threadIdx.x) >> 6;
    int lane = threadIdx.x & 63;
    int g = lane >> 3, q = lane & 7;
    if (wid >= N_NODES) return;
    float a[8] = {0.f, 0.f, 0.f, 0.f, 0.f, 0.f, 0.f, 0.f};
    int e0 = row_ptr[wid], e1 = row_ptr[wid + 1];
    uint4 selfv = {0, 0, 0, 0};
    if (g == 0) selfv = t4[(size_t)wid * 8 + q];
    for (int base = e0; base < e1; base += 8) {
        int ee = base + g;
        if (ee < e1) {
            int s = col[ee];
            uint4 v = t4[(size_t)s * 8 + q];
            a[0] += bflo(v.x); a[1] += bfhi(v.x);
            a[2] += bflo(v.y); a[3] += bfhi(v.y);
            a[4] += bflo(v.z); a[5] += bfhi(v.z);
            a[6] += bflo(v.w); a[7] += bfhi(v.w);
        }
    }
    if (g == 0) {
        a[0] += bflo(selfv.x); a[1] += bfhi(selfv.x);
        a[2] += bflo(selfv.y); a[3] += bfhi(selfv.y);
        a[4] += bflo(selfv.z); a[5] += bfhi(selfv.z);
        a[6] += bflo(selfv.w); a[7] += bfhi(selfv.w);
    }
#pragma unroll
    for (int off = 8; off <= 32; off <<= 1) {
#pragma unroll
        for (int j = 0; j < 8; j++) a[j] += __shfl_xor(a[j], off);
    }
    if (g == 0) {
        float di = dinv[wid];
        float4 b0v = reinterpret_cast<const float4*>(bias)[q * 2];
        float4 b1v = reinterpret_cast<const float4*>(bias)[q * 2 + 1];
        float r[8];
        r[0] = fmaxf(di * a[0] + b0v.x, 0.f);
        r[1] = fmaxf(di * a[1] + b0v.y, 0.f);
        r[2] = fmaxf(di * a[2] + b0v.z, 0.f);
        r[3] = fmaxf(di * a[3] + b0v.w, 0.f);
        r[4] = fmaxf(di * a[4] + b1v.x, 0.f);
        r[5] = fmaxf(di * a[5] + b1v.y, 0.f);
        r[6] = fmaxf(di * a[6] + b1v.z, 0.f);
        r[7] = fmaxf(di * a[7] + b1v.w, 0.f);
        if (OUT_BF16) {
            uint4 o;
            o.x = f2bf(r[0]) | (f2bf(r[1]) << 16);
            o.y = f2bf(r[2]) | (f2bf(r[3]) << 16);
            o.z = f2bf(r[4]) | (f2bf(r[5]) << 16);
            o.w = f2bf(r[6]) | (f2bf(r[7]) << 16);
            ((uint4*)out)[(size_t)wid * 8 + q] = o;
        } else {
            float4* orow = (float4*)((float*)out + (size_t)wid * HID + q * 8);
            orow[0] = (float4){r[0], r[1], r[2], r[3]};
            orow[1] = (float4){r[4], r[5], r[6], r[7]};
        }
    }
}

// ---------------- launch ----------------

extern "C" void kernel_launch(void* const* d_in, const int* in_sizes, int n_in,
                              void* d_out, int out_size, void* d_ws, size_t ws_size,
                              hipStream_t stream) {
    const float* x = (const float*)d_in[0];
    const int* ei = (const int*)d_in[1];
    const int4* src4 = (const int4*)ei;
    const int4* dst4 = (const int4*)(ei + N_EDGES);
    const float* bn0_g = (const float*)d_in[2];
    const float* bn0_b = (const float*)d_in[3];
    const float* W0 = (const float*)d_in[4];
    const float* b0 = (const float*)d_in[5];
    const float* bns_g = (const float*)d_in[6];
    const float* bns_b = (const float*)d_in[7];
    const float* Ws = (const float*)d_in[8];
    const float* bs = (const float*)d_in[9];
    float* out = (float*)d_out;
    char* ws = (char*)d_ws;

    // workspace layout (bytes); rank and h1 alias xb (disjoint lifetimes)
    float*  dinv    = (float*)(ws + 0);          //   400,128
    int*    cnt     = (int*)(ws + 400128);       //   400,128
    int*    row_ptr = (int*)(ws + 800256);       //   400,384
    int*    col     = (int*)(ws + 1200640);      // 4,800,000
    int*    bsum    = (int*)(ws + 6000640);      //       512
    float*  sums    = (float*)(ws + 6001152);    //     2,560
    char*   xb      = (ws + 6003712);            // 25,600,000 (bf16 x)
    int*    rank    = (int*)xb;                  // 4.8MB, dead before xb written
    ushort* h1      = (ushort*)xb;               // 12.8MB, written after xb dead
    ushort* h0      = (ushort*)(ws + 31603712);  // 12,800,000
    ushort* h2      = h0;                        // reuse (h0 dead after gemm1)
    ushort* tbuf    = (ushort*)(ws + 44403712);  // 12,800,000 -> 57.2MB total
    float* sums0 = sums;
    float* sums1 = sums + 256;
    float* sums2 = sums + 384;
    float* sums3 = sums + 512;

    const int EB4 = (E4 + 255) / 256;
    const int NB = (N_NODES + 255) / 256;
    const int GEMM_B = (N_NODES + 63) / 64;   // 1563
    const int AGG_B = (N_NODES + 3) / 4;      // 25000

    // ---- CSR build ----
    hipMemsetAsync(cnt, 0, N_NODES * sizeof(int), stream);
    hipMemsetAsync(sums, 0, 640 * sizeof(float), stream);
    k_hist_rank<<<EB4, 256, 0, stream>>>(dst4, cnt, (int4*)rank);
    k_scan_block<<<SCAN_NBLK, 256, 0, stream>>>(cnt, row_ptr, bsum, dinv);
    k_scan_bsum<<<1, 64, 0, stream>>>(bsum, SCAN_NBLK);
    k_scan_add<<<NB, 256, 0, stream>>>(row_ptr, bsum);
    k_fill<<<EB4, 256, 0, stream>>>(src4, dst4, (const int4*)rank, row_ptr, col);

    // ---- layer 0: stats(x)+x->bf16; BN+Linear+ReLU via MFMA -> h0 bf16 ----
    k_stats_in<<<500, 256, 0, stream>>>((const float4*)x, (uint2*)xb, sums0);
    k_gemm_mfma<IN_F, true><<<GEMM_B, 256, 0, stream>>>((const ushort*)xb, W0, sums0,
                                                        bn0_g, bn0_b, b0, nullptr, h0);

    // ---- layer 1 ----
    k_stats_h<<<400, 256, 0, stream>>>((const uint4*)h0, sums1);
    k_gemm_mfma<HID, false><<<GEMM_B, 256, 0, stream>>>(h0, Ws, sums1, bns_g, bns_b,
                                                        nullptr, dinv, tbuf);
    k_agg<true><<<AGG_B, 256, 0, stream>>>((const uint4*)tbuf, row_ptr, col, dinv, bs, h1);

    // ---- layer 2 ----
    k_stats_h<<<400, 256, 0, stream>>>((const uint4*)h1, sums2);
    k_gemm_mfma<HID, false><<<GEMM_B, 256, 0, stream>>>(h1, Ws + HID * HID, sums2,
                                                        bns_g + HID, bns_b + HID,
                                                        nullptr, dinv, tbuf);
    k_agg<true><<<AGG_B, 256, 0, stream>>>((const uint4*)tbuf, row_ptr, col, dinv,
                                           bs + HID, h2);

    // ---- layer 3 (f32 out) ----
    k_stats_h<<<400, 256, 0, stream>>>((const uint4*)h2, sums3);
    k_gemm_mfma<HID, false><<<GEMM_B, 256, 0, stream>>>(h2, Ws + 2 * HID * HID, sums3,
                                                        bns_g + 2 * HID, bns_b + 2 * HID,
                                                        nullptr, dinv, tbuf);
    k_agg<false><<<AGG_B, 256, 0, stream>>>((const uint4*)tbuf, row_ptr, col, dinv,
                                            bs + 2 * HID, out);
}

// Round 5
// 323.453 us; speedup vs baseline: 2.2488x; 1.0866x over previous
//
#include <hip/hip_runtime.h>

#define N_NODES 100000
#define N_EDGES 1200000
#define IN_F 128
#define HID 64
#define BN_EPS 1e-5f
#define SCAN_NBLK 98   // 98 * 1024 >= 100000
#define E4 (N_EDGES / 4)
#define HB 586         // hist/fill blocks: 8 edges (2 int4) per thread
#define SB 500         // stats_in virtual blocks
#define GEMM_B 1563    // ceil(100000/64)

typedef unsigned int uint;
typedef unsigned short ushort;
typedef __attribute__((ext_vector_type(8))) short bf16x8;
typedef __attribute__((ext_vector_type(4))) float f32x4;

__device__ inline uint f2bf(float f) {        // f32 -> bf16 (RNE), low 16 bits
    uint u = __float_as_uint(f);
    return (u + 0x7fffu + ((u >> 16) & 1u)) >> 16;
}
__device__ inline float bflo(uint v) { return __uint_as_float(v << 16); }
__device__ inline float bfhi(uint v) { return __uint_as_float(v & 0xffff0000u); }

// ---------------- fused: edge histogram+rank  ||  stats(x)+x->bf16 ----------------
__global__ __launch_bounds__(256) void k_hist_stats(
    const int4* __restrict__ dst4, int* __restrict__ cnt, int4* __restrict__ rank4,
    const float4* __restrict__ x4, uint2* __restrict__ xb, float* __restrict__ sums) {
    __shared__ float lds[4][32][8];
    int t = threadIdx.x;
    if (blockIdx.x < HB) {
        int i0 = blockIdx.x * 512 + t;
        int i1 = i0 + 256;
        bool v0 = i0 < E4, v1 = i1 < E4;
        int4 d0, d1, r0, r1;
        if (v0) d0 = dst4[i0];
        if (v1) d1 = dst4[i1];
        if (v0) {
            r0.x = atomicAdd(&cnt[d0.x], 1);
            r0.y = atomicAdd(&cnt[d0.y], 1);
            r0.z = atomicAdd(&cnt[d0.z], 1);
            r0.w = atomicAdd(&cnt[d0.w], 1);
        }
        if (v1) {
            r1.x = atomicAdd(&cnt[d1.x], 1);
            r1.y = atomicAdd(&cnt[d1.y], 1);
            r1.z = atomicAdd(&cnt[d1.z], 1);
            r1.w = atomicAdd(&cnt[d1.w], 1);
        }
        if (v0) rank4[i0] = r0;
        if (v1) rank4[i1] = r1;
        return;
    }
    // ---- stats_in path ----
    int vb = blockIdx.x - HB;
    int cq = t & 31, rs = t >> 5;
    float s1[4] = {0.f, 0.f, 0.f, 0.f}, s2[4] = {0.f, 0.f, 0.f, 0.f};
    for (int r = vb * 8 + rs; r < N_NODES; r += SB * 8) {
        float4 v = x4[(size_t)r * 32 + cq];
        s1[0] += v.x; s2[0] += v.x * v.x;
        s1[1] += v.y; s2[1] += v.y * v.y;
        s1[2] += v.z; s2[2] += v.z * v.z;
        s1[3] += v.w; s2[3] += v.w * v.w;
        uint2 p;
        p.x = f2bf(v.x) | (f2bf(v.y) << 16);
        p.y = f2bf(v.z) | (f2bf(v.w) << 16);
        xb[(size_t)r * 32 + cq] = p;
    }
#pragma unroll
    for (int j = 0; j < 4; j++) {
        s1[j] += __shfl_xor(s1[j], 32);
        s2[j] += __shfl_xor(s2[j], 32);
    }
    int w = t >> 6;
    if ((t & 63) < 32) {
#pragma unroll
        for (int j = 0; j < 4; j++) {
            lds[w][cq][j] = s1[j];
            lds[w][cq][4 + j] = s2[j];
        }
    }
    __syncthreads();
    {
        int cq2 = t >> 3, k = t & 7;
        float v = lds[0][cq2][k] + lds[1][cq2][k] + lds[2][cq2][k] + lds[3][cq2][k];
        int col = cq2 * 4 + (k & 3);
        atomicAdd(&sums[(k >> 2) * 128 + col], v);
    }
}

// ---------------- scan ----------------
__global__ void k_scan_block(const int* __restrict__ cnt, int* __restrict__ outv,
                             int* __restrict__ bsum, float* __restrict__ dinv) {
    __shared__ int lds[256];
    int t = threadIdx.x;
    int base = blockIdx.x * 1024 + t * 4;
    int v[4];
#pragma unroll
    for (int q = 0; q < 4; q++) {
        int idx = base + q;
        v[q] = (idx < N_NODES) ? cnt[idx] : 0;
        if (idx < N_NODES) dinv[idx] = rsqrtf((float)(v[q] + 1));
    }
    int tot = v[0] + v[1] + v[2] + v[3];
    lds[t] = tot;
    __syncthreads();
    int x = tot;
    for (int off = 1; off < 256; off <<= 1) {
        int y = (t >= off) ? lds[t - off] : 0;
        __syncthreads();
        x += y;
        lds[t] = x;
        __syncthreads();
    }
    int run = x - tot;
    if (t == 255) bsum[blockIdx.x] = x;
#pragma unroll
    for (int q = 0; q < 4; q++) {
        int idx = base + q;
        if (idx < N_NODES) outv[idx] = run;
        run += v[q];
    }
}

__global__ void k_scan_bsum(int* bsum, int nb) {
    if (threadIdx.x == 0 && blockIdx.x == 0) {
        int run = 0;
        for (int b = 0; b < nb; b++) { int t = bsum[b]; bsum[b] = run; run += t; }
    }
}

__global__ void k_scan_add(int* __restrict__ row_ptr, const int* __restrict__ bsum) {
    int i = blockIdx.x * 256 + threadIdx.x;
    if (i < N_NODES) row_ptr[i] += bsum[i >> 10];
    if (i == 0) row_ptr[N_NODES] = N_EDGES;
}

// ---------------- MFMA GEMM body (device) ----------------
template <int K, bool LAYER0>
__device__ __forceinline__ void gemm_body(
    int bid, const ushort* __restrict__ h, const float* __restrict__ W,
    const float* __restrict__ sums, const float* __restrict__ gamma,
    const float* __restrict__ beta, const float* __restrict__ bias,
    const float* __restrict__ dinv, ushort* __restrict__ out) {
    __shared__ ushort Alds[64 * K];
    __shared__ ushort Wt[64 * K];
    __shared__ float scale_s[K], shift_s[K], shW[HID];
    const int KB = K * 2;
    int t = threadIdx.x;
    if (t < K) {
        float m = sums[t] * (1.0f / N_NODES);
        float var = sums[K + t] * (1.0f / N_NODES) - m * m;
        float sc = gamma[t] * rsqrtf(var + BN_EPS);
        scale_s[t] = sc;
        shift_s[t] = beta[t] - m * sc;
    }
    __syncthreads();
    for (int idx = t; idx < K * 64; idx += 256) {
        int k = idx >> 6, n = idx & 63;
        float v = W[idx] * scale_s[k];
        int byte = n * KB + k * 2;
        byte ^= ((n & 7) << 4);
        *(ushort*)((char*)Wt + byte) = (ushort)f2bf(v);
    }
    if (t < HID) {
        float acc = 0.f;
#pragma unroll 4
        for (int k = 0; k < K; k++) acc += shift_s[k] * W[k * HID + t];
        shW[t] = acc;
    }
    int row0 = bid * 64;
    {
        const int KG = K / 8;
        for (int idx = t; idx < 64 * KG; idx += 256) {
            int r = idx / KG, kg = idx % KG;
            int rr = row0 + r;
            if (rr >= N_NODES) rr = N_NODES - 1;
            uint4 v = *(const uint4*)(h + (size_t)rr * K + kg * 8);
            int byte = r * KB + kg * 16;
            byte ^= ((r & 7) << 4);
            *(uint4*)((char*)Alds + byte) = v;
        }
    }
    __syncthreads();

    int w = t >> 6, l = t & 63;
    int lr = l & 15, lg = l >> 4;
    f32x4 acc[4];
#pragma unroll
    for (int nt = 0; nt < 4; nt++) {
        float s = shW[nt * 16 + lr];
        acc[nt] = (f32x4){s, s, s, s};
    }
#pragma unroll
    for (int c = 0; c < K / 32; c++) {
        int arow = w * 16 + lr;
        int abyte = (arow * KB + c * 64 + lg * 16) ^ ((arow & 7) << 4);
        bf16x8 a = *(const bf16x8*)((const char*)Alds + abyte);
#pragma unroll
        for (int nt = 0; nt < 4; nt++) {
            int n = nt * 16 + lr;
            int bbyte = (n * KB + c * 64 + lg * 16) ^ ((n & 7) << 4);
            bf16x8 b = *(const bf16x8*)((const char*)Wt + bbyte);
            acc[nt] = __builtin_amdgcn_mfma_f32_16x16x32_bf16(a, b, acc[nt], 0, 0, 0);
        }
    }
    int wrow0 = row0 + w * 16;
    char* myA = (char*)Alds + w * 16 * KB;
    float4 dv = {0.f, 0.f, 0.f, 0.f};
    float bias_v[4];
    if (LAYER0) {
#pragma unroll
        for (int nt = 0; nt < 4; nt++) bias_v[nt] = bias[nt * 16 + lr];
    } else {
        int dbase = wrow0 + lg * 4;
        if (dbase > N_NODES - 4) dbase = N_NODES - 4;
        dv = *(const float4*)(dinv + dbase);
    }
    float dvv[4] = {dv.x, dv.y, dv.z, dv.w};
#pragma unroll
    for (int nt = 0; nt < 4; nt++) {
#pragma unroll
        for (int r = 0; r < 4; r++) {
            float v = acc[nt][r];
            if (LAYER0) v = fmaxf(v + bias_v[nt], 0.f);
            else v = v * dvv[r];
            int rowl = lg * 4 + r;
            int byte = (rowl * 128 + (nt * 16 + lr) * 2) ^ ((rowl & 7) << 4);
            *(ushort*)(myA + byte) = (ushort)f2bf(v);
        }
    }
    {
        int rowl0 = l >> 3, kg0 = l & 7;
        int b0 = (rowl0 * 128 + kg0 * 16) ^ ((rowl0 & 7) << 4);
        int rowl1 = 8 + (l >> 3);
        int b1 = (rowl1 * 128 + kg0 * 16) ^ ((rowl1 & 7) << 4);
        uint4 v0 = *(uint4*)(myA + b0);
        uint4 v1 = *(uint4*)(myA + b1);
        size_t gg = (size_t)wrow0 * 128 + l * 16;
        if (wrow0 + rowl0 < N_NODES) *(uint4*)((char*)out + gg) = v0;
        if (wrow0 + rowl1 < N_NODES) *(uint4*)((char*)out + gg + 1024) = v1;
    }
}

// ---------------- fused: CSR fill || gemm0 ----------------
__global__ __launch_bounds__(256) void k_fill_gemm0(
    const int4* __restrict__ src4, const int4* __restrict__ dst4,
    const int4* __restrict__ rank4, const int* __restrict__ row_ptr,
    int* __restrict__ col, const ushort* __restrict__ xb, const float* __restrict__ W0,
    const float* __restrict__ sums0, const float* __restrict__ gamma,
    const float* __restrict__ beta, const float* __restrict__ bias,
    ushort* __restrict__ h0) {
    if (blockIdx.x < HB) {
        int t = threadIdx.x;
        int i0 = blockIdx.x * 512 + t;
        int i1 = i0 + 256;
#pragma unroll
        for (int p = 0; p < 2; p++) {
            int i = p ? i1 : i0;
            if (i < E4) {
                int4 s = src4[i];
                int4 d = dst4[i];
                int4 r = rank4[i];
                col[row_ptr[d.x] + r.x] = s.x;
                col[row_ptr[d.y] + r.y] = s.y;
                col[row_ptr[d.z] + r.z] = s.z;
                col[row_ptr[d.w] + r.w] = s.w;
            }
        }
        return;
    }
    gemm_body<IN_F, true>(blockIdx.x - HB, xb, W0, sums0, gamma, beta, bias, nullptr, h0);
}

// standalone K=64 gemm
__global__ __launch_bounds__(256) void k_gemm64(
    const ushort* __restrict__ h, const float* __restrict__ W,
    const float* __restrict__ sums, const float* __restrict__ gamma,
    const float* __restrict__ beta, const float* __restrict__ dinv,
    ushort* __restrict__ out) {
    gemm_body<HID, false>(blockIdx.x, h, W, sums, gamma, beta, nullptr, dinv, out);
}

// ---------------- stats on bf16 h (C=64, post-relu rows) ----------------
__global__ __launch_bounds__(256) void k_stats_h(const uint4* __restrict__ h4,
                                                 float* __restrict__ sums) {
    __shared__ float lds[4][8][16];
    int t = threadIdx.x;
    int cg = t & 7, rs = t >> 3;
    float s1[8], s2[8];
#pragma unroll
    for (int j = 0; j < 8; j++) { s1[j] = 0.f; s2[j] = 0.f; }
    for (int r = blockIdx.x * 32 + rs; r < N_NODES; r += gridDim.x * 32) {
        uint4 v = h4[(size_t)r * 8 + cg];
        float f;
        f = bflo(v.x); s1[0] += f; s2[0] += f * f;
        f = bfhi(v.x); s1[1] += f; s2[1] += f * f;
        f = bflo(v.y); s1[2] += f; s2[2] += f * f;
        f = bfhi(v.y); s1[3] += f; s2[3] += f * f;
        f = bflo(v.z); s1[4] += f; s2[4] += f * f;
        f = bfhi(v.z); s1[5] += f; s2[5] += f * f;
        f = bflo(v.w); s1[6] += f; s2[6] += f * f;
        f = bfhi(v.w); s1[7] += f; s2[7] += f * f;
    }
#pragma unroll
    for (int off = 8; off <= 32; off <<= 1) {
#pragma unroll
        for (int j = 0; j < 8; j++) {
            s1[j] += __shfl_xor(s1[j], off);
            s2[j] += __shfl_xor(s2[j], off);
        }
    }
    int w = t >> 6;
    if ((t & 63) < 8) {
#pragma unroll
        for (int j = 0; j < 8; j++) {
            lds[w][cg][j] = s1[j];
            lds[w][cg][8 + j] = s2[j];
        }
    }
    __syncthreads();
    if (t < 128) {
        int cg2 = t >> 4, k = t & 15;
        float v = lds[0][cg2][k] + lds[1][cg2][k] + lds[2][cg2][k] + lds[3][cg2][k];
        int col = cg2 * 8 + (k & 7);
        atomicAdd(&sums[(k >> 3) * 64 + col], v);
    }
}

// ---------------- per-node gather aggregation (bf16 rows, shfl-broadcast col) ----------------
template <bool OUT_BF16>
__global__ __launch_bounds__(256) void k_agg(const uint4* __restrict__ t4,
                                             const int* __restrict__ row_ptr,
                                             const int* __restrict__ col,
                                             const float* __restrict__ dinv,
                                             const float* __restrict__ bias,
                                             void* __restrict__ out) {
    int wid = (blockIdx.x * 256 + threadIdx.x) >> 6;
    int lane = threadIdx.x & 63;
    int g = lane >> 3, q = lane & 7;
    if (wid >= N_NODES) return;
    int e0 = row_ptr[wid], e1 = row_ptr[wid + 1];
    int deg = e1 - e0;
    int ce = e0 + lane;
    int cidx = col[(ce < e1) ? ce : 0];   // one coalesced load covers 64 edges
    float a[8] = {0.f, 0.f, 0.f, 0.f, 0.f, 0.f, 0.f, 0.f};
    uint4 selfv = {0, 0, 0, 0};
    if (g == 0) selfv = t4[(size_t)wid * 8 + q];
    int degc = deg < 64 ? deg : 64;
    for (int d = 0; d < degc; d += 32) {
        int s[4];
        bool val[4];
#pragma unroll
        for (int j = 0; j < 4; j++) {
            int idx = d + j * 8 + g;
            val[j] = idx < degc;
            s[j] = __shfl(cidx, idx & 63);
        }
        uint4 v[4];
#pragma unroll
        for (int j = 0; j < 4; j++)
            v[j] = t4[(size_t)(val[j] ? s[j] : wid) * 8 + q];  // 4 gathers in flight
#pragma unroll
        for (int j = 0; j < 4; j++) {
            if (val[j]) {
                a[0] += bflo(v[j].x); a[1] += bfhi(v[j].x);
                a[2] += bflo(v[j].y); a[3] += bfhi(v[j].y);
                a[4] += bflo(v[j].z); a[5] += bfhi(v[j].z);
                a[6] += bflo(v[j].w); a[7] += bfhi(v[j].w);
            }
        }
    }
    for (int base = e0 + 64; base < e1; base += 8) {   // deg>64: astronomically rare
        int ee = base + g;
        if (ee < e1) {
            int s = col[ee];
            uint4 v = t4[(size_t)s * 8 + q];
            a[0] += bflo(v.x); a[1] += bfhi(v.x);
            a[2] += bflo(v.y); a[3] += bfhi(v.y);
            a[4] += bflo(v.z); a[5] += bfhi(v.z);
            a[6] += bflo(v.w); a[7] += bfhi(v.w);
        }
    }
    if (g == 0) {
        a[0] += bflo(selfv.x); a[1] += bfhi(selfv.x);
        a[2] += bflo(selfv.y); a[3] += bfhi(selfv.y);
        a[4] += bflo(selfv.z); a[5] += bfhi(selfv.z);
        a[6] += bflo(selfv.w); a[7] += bfhi(selfv.w);
    }
#pragma unroll
    for (int off = 8; off <= 32; off <<= 1) {
#pragma unroll
        for (int j = 0; j < 8; j++) a[j] += __shfl_xor(a[j], off);
    }
    if (g == 0) {
        float di = dinv[wid];
        float4 b0v = reinterpret_cast<const float4*>(bias)[q * 2];
        float4 b1v = reinterpret_cast<const float4*>(bias)[q * 2 + 1];
        float r[8];
        r[0] = fmaxf(di * a[0] + b0v.x, 0.f);
        r[1] = fmaxf(di * a[1] + b0v.y, 0.f);
        r[2] = fmaxf(di * a[2] + b0v.z, 0.f);
        r[3] = fmaxf(di * a[3] + b0v.w, 0.f);
        r[4] = fmaxf(di * a[4] + b1v.x, 0.f);
        r[5] = fmaxf(di * a[5] + b1v.y, 0.f);
        r[6] = fmaxf(di * a[6] + b1v.z, 0.f);
        r[7] = fmaxf(di * a[7] + b1v.w, 0.f);
        if (OUT_BF16) {
            uint4 o;
            o.x = f2bf(r[0]) | (f2bf(r[1]) << 16);
            o.y = f2bf(r[2]) | (f2bf(r[3]) << 16);
            o.z = f2bf(r[4]) | (f2bf(r[5]) << 16);
            o.w = f2bf(r[6]) | (f2bf(r[7]) << 16);
            ((uint4*)out)[(size_t)wid * 8 + q] = o;
        } else {
            float4* orow = (float4*)((float*)out + (size_t)wid * HID + q * 8);
            orow[0] = (float4){r[0], r[1], r[2], r[3]};
            orow[1] = (float4){r[4], r[5], r[6], r[7]};
        }
    }
}

// ---------------- launch ----------------

extern "C" void kernel_launch(void* const* d_in, const int* in_sizes, int n_in,
                              void* d_out, int out_size, void* d_ws, size_t ws_size,
                              hipStream_t stream) {
    const float* x = (const float*)d_in[0];
    const int* ei = (const int*)d_in[1];
    const int4* src4 = (const int4*)ei;
    const int4* dst4 = (const int4*)(ei + N_EDGES);
    const float* bn0_g = (const float*)d_in[2];
    const float* bn0_b = (const float*)d_in[3];
    const float* W0 = (const float*)d_in[4];
    const float* b0 = (const float*)d_in[5];
    const float* bns_g = (const float*)d_in[6];
    const float* bns_b = (const float*)d_in[7];
    const float* Ws = (const float*)d_in[8];
    const float* bs = (const float*)d_in[9];
    float* out = (float*)d_out;
    char* ws = (char*)d_ws;

    // workspace layout (bytes); h1 aliases xb (xb dead after gemm0)
    float*  dinv    = (float*)(ws + 0);          //   400,128
    int*    cnt     = (int*)(ws + 400128);       //   400,128
    int*    row_ptr = (int*)(ws + 800256);       //   400,384
    int*    col     = (int*)(ws + 1200640);      // 4,800,000
    int*    bsum    = (int*)(ws + 6000640);      //       512
    float*  sums    = (float*)(ws + 6001152);    //     2,560
    int*    rank    = (int*)(ws + 6003712);      // 4,800,000
    char*   xb      = (ws + 10803712);           // 25,600,000 (bf16 x)
    ushort* h1      = (ushort*)xb;               // 12.8MB, written after xb dead
    ushort* h0      = (ushort*)(ws + 36403712);  // 12,800,000
    ushort* h2      = h0;                        // reuse
    ushort* tbuf    = (ushort*)(ws + 49203712);  // 12,800,000 -> 62,003,712 total
    float* sums0 = sums;
    float* sums1 = sums + 256;
    float* sums2 = sums + 384;
    float* sums3 = sums + 512;

    const int NB = (N_NODES + 255) / 256;
    const int AGG_B = (N_NODES + 3) / 4;      // 25000

    hipMemsetAsync(cnt, 0, N_NODES * sizeof(int), stream);
    hipMemsetAsync(sums, 0, 640 * sizeof(float), stream);

    // ---- K1: edge histogram+rank || stats(x)+x->bf16 ----
    k_hist_stats<<<HB + SB, 256, 0, stream>>>(dst4, cnt, (int4*)rank, (const float4*)x,
                                              (uint2*)xb, sums0);
    // ---- scan ----
    k_scan_block<<<SCAN_NBLK, 256, 0, stream>>>(cnt, row_ptr, bsum, dinv);
    k_scan_bsum<<<1, 64, 0, stream>>>(bsum, SCAN_NBLK);
    k_scan_add<<<NB, 256, 0, stream>>>(row_ptr, bsum);

    // ---- K3: CSR fill || gemm0 (BN+Linear+ReLU -> h0 bf16) ----
    k_fill_gemm0<<<HB + GEMM_B, 256, 0, stream>>>(src4, dst4, (const int4*)rank, row_ptr, col,
                                                  (const ushort*)xb, W0, sums0, bn0_g, bn0_b,
                                                  b0, h0);

    // ---- layer 1 ----
    k_stats_h<<<400, 256, 0, stream>>>((const uint4*)h0, sums1);
    k_gemm64<<<GEMM_B, 256, 0, stream>>>(h0, Ws, sums1, bns_g, bns_b, dinv, tbuf);
    k_agg<true><<<AGG_B, 256, 0, stream>>>((const uint4*)tbuf, row_ptr, col, dinv, bs, h1);

    // ---- layer 2 ----
    k_stats_h<<<400, 256, 0, stream>>>((const uint4*)h1, sums2);
    k_gemm64<<<GEMM_B, 256, 0, stream>>>(h1, Ws + HID * HID, sums2, bns_g + HID,
                                         bns_b + HID, dinv, tbuf);
    k_agg<true><<<AGG_B, 256, 0, stream>>>((const uint4*)tbuf, row_ptr, col, dinv,
                                           bs + HID, h2);

    // ---- layer 3 (f32 out) ----
    k_stats_h<<<400, 256, 0, stream>>>((const uint4*)h2, sums3);
    k_gemm64<<<GEMM_B, 256, 0, stream>>>(h2, Ws + 2 * HID * HID, sums3, bns_g + 2 * HID,
                                         bns_b + 2 * HID, dinv, tbuf);
    k_agg<false><<<AGG_B, 256, 0, stream>>>((const uint4*)tbuf, row_ptr, col, dinv,
                                            bs + 2 * HID, out);
}